// Round 1
// baseline (508.440 us; speedup 1.0000x reference)
//
#include <hip/hip_runtime.h>
#include <hip/hip_bf16.h>
#include <math.h>

#define HID 128
#define NH  8

// ---------------- projection: out = (h @ W.T + b) * scale ----------------
// grid.x = ceil(N/64), grid.y = 3 (q,k,v). block = 256.
// thread t: row-group rg = t>>4 (4 rows), col-group cg = t&15, cols c = cg + 16j.
__global__ __launch_bounds__(256) void proj_kernel(
    const float* __restrict__ h,
    const float* __restrict__ Wq, const float* __restrict__ bq,
    const float* __restrict__ Wk, const float* __restrict__ bk,
    const float* __restrict__ Wv, const float* __restrict__ bv,
    float* __restrict__ qo, float* __restrict__ ko, float* __restrict__ vo,
    int n) {
  __shared__ float wl[HID * HID];  // 64 KB
  const float* W; const float* b; float* o; float scale;
  if (blockIdx.y == 0)      { W = Wq; b = bq; o = qo; scale = 0.25f; } // DH^-0.5 = 16^-0.5
  else if (blockIdx.y == 1) { W = Wk; b = bk; o = ko; scale = 1.0f; }
  else                      { W = Wv; b = bv; o = vo; scale = 1.0f; }

  int t = threadIdx.x;
  // stage W (16384 floats) as float4, flat copy
  for (int i = t; i < HID * HID / 4; i += 256) {
    ((float4*)wl)[i] = ((const float4*)W)[i];
  }
  __syncthreads();

  int rg = t >> 4;
  int cg = t & 15;
  int r0 = blockIdx.x * 64 + rg * 4;

  float acc[4][8];
#pragma unroll
  for (int i = 0; i < 4; ++i)
#pragma unroll
    for (int j = 0; j < 8; ++j) acc[i][j] = 0.f;

  for (int k4 = 0; k4 < 32; ++k4) {
    int kk = (k4 + cg) & 31;  // per-lane rotation: LDS bank-base stride 4/lane -> 2-way max
    float4 hv[4];
#pragma unroll
    for (int i = 0; i < 4; ++i) {
      if (r0 + i < n)
        hv[i] = ((const float4*)(h + (size_t)(r0 + i) * HID))[kk];
      else
        hv[i] = make_float4(0.f, 0.f, 0.f, 0.f);
    }
#pragma unroll
    for (int j = 0; j < 8; ++j) {
      int c = cg + 16 * j;
      float4 wv = *(const float4*)&wl[c * HID + kk * 4];
#pragma unroll
      for (int i = 0; i < 4; ++i) {
        acc[i][j] += hv[i].x * wv.x + hv[i].y * wv.y + hv[i].z * wv.z + hv[i].w * wv.w;
      }
    }
  }

#pragma unroll
  for (int i = 0; i < 4; ++i) {
    int r = r0 + i;
    if (r >= n) break;
#pragma unroll
    for (int j = 0; j < 8; ++j) {
      int c = cg + 16 * j;
      o[(size_t)r * HID + c] = (acc[i][j] + b[c]) * scale;
    }
  }
}

// ---------------- CSR build ----------------
__global__ void hist_kernel(const int* __restrict__ src, int* __restrict__ deg, int e) {
  int i = blockIdx.x * blockDim.x + threadIdx.x;
  if (i < e) atomicAdd(&deg[src[i]], 1);
}

__global__ void scan_kernel(const int* __restrict__ deg, int* __restrict__ rowptr, int n) {
  __shared__ int part[1024];
  int t = threadIdx.x;
  int ch = (n + 1023) / 1024;
  int base = t * ch;
  int s = 0;
  for (int i = 0; i < ch; ++i) {
    int idx = base + i;
    if (idx < n) s += deg[idx];
  }
  part[t] = s;
  __syncthreads();
  for (int off = 1; off < 1024; off <<= 1) {
    int v = (t >= off) ? part[t - off] : 0;
    __syncthreads();
    part[t] += v;
    __syncthreads();
  }
  int excl = part[t] - s;
  for (int i = 0; i < ch; ++i) {
    int idx = base + i;
    if (idx < n) { rowptr[idx] = excl; excl += deg[idx]; }
  }
  if (t == 1023) rowptr[n] = part[1023];
}

__global__ void scatter_kernel(const int* __restrict__ src, const int* __restrict__ dst,
                               const float* __restrict__ val,
                               const int* __restrict__ rowptr, int* __restrict__ cursor,
                               int* __restrict__ csr_dst, float* __restrict__ csr_val, int e) {
  int i = blockIdx.x * blockDim.x + threadIdx.x;
  if (i < e) {
    int s = src[i];
    int p = atomicAdd(&cursor[s], 1);
    int idx = rowptr[s] + p;
    csr_dst[idx] = dst[i];
    csr_val[idx] = val[i];
  }
}

// ---------------- per-node online-softmax attention ----------------
// one wave (64 lanes) per node; lane l owns features l and l+64 (head = l%8).
__global__ __launch_bounds__(256) void node_kernel(
    const float* __restrict__ q, const float* __restrict__ k, const float* __restrict__ v,
    const int* __restrict__ rowptr, const int* __restrict__ csr_dst,
    const float* __restrict__ csr_val,
    float* __restrict__ out, int n) {
  int wid = (blockIdx.x * blockDim.x + threadIdx.x) >> 6;
  int lane = threadIdx.x & 63;
  if (wid >= n) return;

  const float* qr = q + (size_t)wid * HID;
  float qa = qr[lane], qb = qr[lane + 64];

  int beg = rowptr[wid], end = rowptr[wid + 1];
  float m = -INFINITY, s = 0.f, o0 = 0.f, o1 = 0.f;

  for (int i = beg; i < end; ++i) {
    int d = csr_dst[i];
    float vale = csr_val[i];
    const float* kr = k + (size_t)d * HID;
    const float* vr = v + (size_t)d * HID;
    float ka = kr[lane], kb = kr[lane + 64];
    float va = vr[lane], vb = vr[lane + 64];
    float p = qa * ka + qb * kb;
    // reduce across lanes with same (lane % 8) -> per-head dot in every lane
    p += __shfl_xor(p, 8);
    p += __shfl_xor(p, 16);
    p += __shfl_xor(p, 32);
    float score = p * vale;
    float mn = fmaxf(m, score);
    float c = __expf(m - mn);      // first iter: exp(-inf)=0
    float w = __expf(score - mn);
    s = s * c + w;
    o0 = o0 * c + w * va;
    o1 = o1 * c + w * vb;
    m = mn;
  }

  float inv = (s > 0.f) ? 1.f / s : 0.f;
  out[(size_t)wid * HID + lane] = o0 * inv;
  out[(size_t)wid * HID + lane + 64] = o1 * inv;
}

// ---------------- launcher ----------------
extern "C" void kernel_launch(void* const* d_in, const int* in_sizes, int n_in,
                              void* d_out, int out_size, void* d_ws, size_t ws_size,
                              hipStream_t stream) {
  const float* h  = (const float*)d_in[0];
  const float* val = (const float*)d_in[1];
  const float* Wq = (const float*)d_in[2];
  const float* bq = (const float*)d_in[3];
  const float* Wk = (const float*)d_in[4];
  const float* bk = (const float*)d_in[5];
  const float* Wv = (const float*)d_in[6];
  const float* bv = (const float*)d_in[7];
  const int* src  = (const int*)d_in[8];
  const int* dst  = (const int*)d_in[9];

  int N = in_sizes[0] / HID;
  int E = in_sizes[8];
  float* out = (float*)d_out;

  // workspace layout
  float* q  = (float*)d_ws;                        // N*128
  float* kk = q  + (size_t)N * HID;                // N*128
  float* vv = kk + (size_t)N * HID;                // N*128
  int* rowptr  = (int*)(vv + (size_t)N * HID);     // N+1
  int* deg     = rowptr + (N + 1);                 // N
  int* cursor  = deg + N;                          // N
  int* csr_dst = cursor + N;                       // E
  float* csr_val = (float*)(csr_dst + E);          // E

  hipMemsetAsync(deg, 0, sizeof(int) * 2 * (size_t)N, stream);  // deg + cursor

  proj_kernel<<<dim3((N + 63) / 64, 3), 256, 0, stream>>>(
      h, Wq, bq, Wk, bk, Wv, bv, q, kk, vv, N);
  hist_kernel<<<(E + 255) / 256, 256, 0, stream>>>(src, deg, E);
  scan_kernel<<<1, 1024, 0, stream>>>(deg, rowptr, N);
  scatter_kernel<<<(E + 255) / 256, 256, 0, stream>>>(
      src, dst, val, rowptr, cursor, csr_dst, csr_val, E);
  node_kernel<<<(N + 3) / 4, 256, 0, stream>>>(
      q, kk, vv, rowptr, csr_dst, csr_val, out, N);
}

// Round 2
// 456.353 us; speedup vs baseline: 1.1141x; 1.1141x over previous
//
#include <hip/hip_runtime.h>
#include <hip/hip_bf16.h>
#include <math.h>

#define HID 128
#define NH  8

// ---------------- projection: out = (h @ W.T + b) * scale ----------------
// grid.x = ceil(N/64), grid.y = 3 (q,k,v). block = 256 (4 waves).
// W staged in LDS in two 64-col halves (32KB) -> 5 blocks/CU occupancy.
// thread t: rg = t>>4 (4 rows), cg = t&15 (4 consecutive cols per half).
__global__ __launch_bounds__(256) void proj_kernel(
    const float* __restrict__ h,
    const float* __restrict__ Wq, const float* __restrict__ bq,
    const float* __restrict__ Wk, const float* __restrict__ bk,
    const float* __restrict__ Wv, const float* __restrict__ bv,
    float* __restrict__ qo, float* __restrict__ ko, float* __restrict__ vo,
    int n) {
  __shared__ float wl[64 * HID];  // 32 KB
  const float* W; const float* b; float* o; float scale;
  if (blockIdx.y == 0)      { W = Wq; b = bq; o = qo; scale = 0.25f; } // DH^-0.5
  else if (blockIdx.y == 1) { W = Wk; b = bk; o = ko; scale = 1.0f; }
  else                      { W = Wv; b = bv; o = vo; scale = 1.0f; }

  const int t = threadIdx.x;
  const int rg = t >> 4;   // 0..15
  const int cg = t & 15;   // 0..15
  const int r0 = blockIdx.x * 64 + rg * 4;

  // hoisted, clamped row pointers: branch-free inner loop
  const float* hp[4];
#pragma unroll
  for (int i = 0; i < 4; ++i) {
    int r = r0 + i;
    if (r > n - 1) r = n - 1;
    hp[i] = h + (size_t)r * HID;
  }

  for (int half = 0; half < 2; ++half) {
    const int c0 = half * 64;
    // stage W[c0..c0+63][0..127] (8 float4 per thread)
    const float4* wsrc = (const float4*)(W + (size_t)c0 * HID);
    for (int i = t; i < 64 * HID / 4; i += 256) ((float4*)wl)[i] = wsrc[i];
    __syncthreads();

    float acc[4][4];
#pragma unroll
    for (int i = 0; i < 4; ++i)
#pragma unroll
      for (int j = 0; j < 4; ++j) acc[i][j] = 0.f;

    for (int k4 = 0; k4 < 32; ++k4) {
      const int kk = (k4 + cg) & 31;  // rotation: <=2-way LDS aliasing (free)
      float4 hv[4];
#pragma unroll
      for (int i = 0; i < 4; ++i) hv[i] = ((const float4*)hp[i])[kk];
#pragma unroll
      for (int j = 0; j < 4; ++j) {
        float4 wv = *(const float4*)&wl[(cg * 4 + j) * HID + kk * 4];
#pragma unroll
        for (int i = 0; i < 4; ++i) {
          acc[i][j] += hv[i].x * wv.x + hv[i].y * wv.y +
                       hv[i].z * wv.z + hv[i].w * wv.w;
        }
      }
    }

#pragma unroll
    for (int i = 0; i < 4; ++i) {
      int r = r0 + i;
      if (r < n) {
        int c = c0 + cg * 4;
        float4 bb = *(const float4*)&b[c];
        float4 res;
        res.x = (acc[i][0] + bb.x) * scale;
        res.y = (acc[i][1] + bb.y) * scale;
        res.z = (acc[i][2] + bb.z) * scale;
        res.w = (acc[i][3] + bb.w) * scale;
        *(float4*)&o[(size_t)r * HID + c] = res;
      }
    }
    __syncthreads();  // all reads of wl done before restage
  }
}

// ---------------- CSR build ----------------
__global__ void hist_kernel(const int* __restrict__ src, int* __restrict__ deg, int e) {
  int i = blockIdx.x * blockDim.x + threadIdx.x;
  if (i < e) atomicAdd(&deg[src[i]], 1);
}

__global__ void scan_kernel(const int* __restrict__ deg, int* __restrict__ rowptr, int n) {
  __shared__ int part[1024];
  int t = threadIdx.x;
  int ch = (n + 1023) / 1024;
  int base = t * ch;
  int s = 0;
  for (int i = 0; i < ch; ++i) {
    int idx = base + i;
    if (idx < n) s += deg[idx];
  }
  part[t] = s;
  __syncthreads();
  for (int off = 1; off < 1024; off <<= 1) {
    int v = (t >= off) ? part[t - off] : 0;
    __syncthreads();
    part[t] += v;
    __syncthreads();
  }
  int excl = part[t] - s;
  for (int i = 0; i < ch; ++i) {
    int idx = base + i;
    if (idx < n) { rowptr[idx] = excl; excl += deg[idx]; }
  }
  if (t == 1023) rowptr[n] = part[1023];
}

__global__ void scatter_kernel(const int* __restrict__ src, const int* __restrict__ dst,
                               const float* __restrict__ val,
                               const int* __restrict__ rowptr, int* __restrict__ cursor,
                               int* __restrict__ csr_dst, float* __restrict__ csr_val, int e) {
  int i = blockIdx.x * blockDim.x + threadIdx.x;
  if (i < e) {
    int s = src[i];
    int p = atomicAdd(&cursor[s], 1);
    int idx = rowptr[s] + p;
    csr_dst[idx] = dst[i];
    csr_val[idx] = val[i];
  }
}

// ---------------- per-node online-softmax attention ----------------
// one wave (64 lanes) per node; lane l owns features l and l+64 (head = l%8).
__global__ __launch_bounds__(256) void node_kernel(
    const float* __restrict__ q, const float* __restrict__ k, const float* __restrict__ v,
    const int* __restrict__ rowptr, const int* __restrict__ csr_dst,
    const float* __restrict__ csr_val,
    float* __restrict__ out, int n) {
  int wid = (blockIdx.x * blockDim.x + threadIdx.x) >> 6;
  int lane = threadIdx.x & 63;
  if (wid >= n) return;

  const float* qr = q + (size_t)wid * HID;
  float qa = qr[lane], qb = qr[lane + 64];

  int beg = rowptr[wid], end = rowptr[wid + 1];
  float m = -INFINITY, s = 0.f, o0 = 0.f, o1 = 0.f;

  for (int i = beg; i < end; ++i) {
    int d = csr_dst[i];
    float vale = csr_val[i];
    const float* kr = k + (size_t)d * HID;
    const float* vr = v + (size_t)d * HID;
    float ka = kr[lane], kb = kr[lane + 64];
    float va = vr[lane], vb = vr[lane + 64];
    float p = qa * ka + qb * kb;
    // reduce across lanes with same (lane % 8) -> per-head dot in every lane
    p += __shfl_xor(p, 8);
    p += __shfl_xor(p, 16);
    p += __shfl_xor(p, 32);
    float score = p * vale;
    float mn = fmaxf(m, score);
    float c = __expf(m - mn);      // first iter: exp(-inf)=0
    float w = __expf(score - mn);
    s = s * c + w;
    o0 = o0 * c + w * va;
    o1 = o1 * c + w * vb;
    m = mn;
  }

  float inv = (s > 0.f) ? 1.f / s : 0.f;
  out[(size_t)wid * HID + lane] = o0 * inv;
  out[(size_t)wid * HID + lane + 64] = o1 * inv;
}

// ---------------- launcher ----------------
extern "C" void kernel_launch(void* const* d_in, const int* in_sizes, int n_in,
                              void* d_out, int out_size, void* d_ws, size_t ws_size,
                              hipStream_t stream) {
  const float* h  = (const float*)d_in[0];
  const float* val = (const float*)d_in[1];
  const float* Wq = (const float*)d_in[2];
  const float* bq = (const float*)d_in[3];
  const float* Wk = (const float*)d_in[4];
  const float* bk = (const float*)d_in[5];
  const float* Wv = (const float*)d_in[6];
  const float* bv = (const float*)d_in[7];
  const int* src  = (const int*)d_in[8];
  const int* dst  = (const int*)d_in[9];

  int N = in_sizes[0] / HID;
  int E = in_sizes[8];
  float* out = (float*)d_out;

  // workspace layout
  float* q  = (float*)d_ws;                        // N*128
  float* kk = q  + (size_t)N * HID;                // N*128
  float* vv = kk + (size_t)N * HID;                // N*128
  int* rowptr  = (int*)(vv + (size_t)N * HID);     // N+1
  int* deg     = rowptr + (N + 1);                 // N
  int* cursor  = deg + N;                          // N
  int* csr_dst = cursor + N;                       // E
  float* csr_val = (float*)(csr_dst + E);          // E

  hipMemsetAsync(deg, 0, sizeof(int) * 2 * (size_t)N, stream);  // deg + cursor

  proj_kernel<<<dim3((N + 63) / 64, 3), 256, 0, stream>>>(
      h, Wq, bq, Wk, bk, Wv, bv, q, kk, vv, N);
  hist_kernel<<<(E + 255) / 256, 256, 0, stream>>>(src, deg, E);
  scan_kernel<<<1, 1024, 0, stream>>>(deg, rowptr, N);
  scatter_kernel<<<(E + 255) / 256, 256, 0, stream>>>(
      src, dst, val, rowptr, cursor, csr_dst, csr_val, E);
  node_kernel<<<(N + 3) / 4, 256, 0, stream>>>(
      q, kk, vv, rowptr, csr_dst, csr_val, out, N);
}

// Round 3
// 339.606 us; speedup vs baseline: 1.4971x; 1.3438x over previous
//
#include <hip/hip_runtime.h>
#include <hip/hip_bf16.h>
#include <math.h>

#define HID 128
#define NH  8

typedef __attribute__((ext_vector_type(8))) short short8;
typedef __attribute__((ext_vector_type(4))) float f32x4;

static __device__ __forceinline__ float bf2f(unsigned short u) {
  union { unsigned int i; float f; } c; c.i = ((unsigned int)u) << 16; return c.f;
}
static __device__ __forceinline__ unsigned short f2bf(float f) {
  union { float f; unsigned int i; } c; c.f = f;
  unsigned int r = c.i + 0x7FFFu + ((c.i >> 16) & 1u);  // round-nearest-even
  return (unsigned short)(r >> 16);
}

// ---------------- fp32 -> bf16 conversion (grid-stride, 8 elems/thread) ----
__global__ void convert_kernel(const float* __restrict__ src,
                               unsigned short* __restrict__ dst, int n8) {
  int stride = gridDim.x * blockDim.x;
  for (int i = blockIdx.x * blockDim.x + threadIdx.x; i < n8; i += stride) {
    float4 a = ((const float4*)src)[2 * i];
    float4 b = ((const float4*)src)[2 * i + 1];
    uint4 o;
    o.x = ((unsigned int)f2bf(a.y) << 16) | f2bf(a.x);
    o.y = ((unsigned int)f2bf(a.w) << 16) | f2bf(a.z);
    o.z = ((unsigned int)f2bf(b.y) << 16) | f2bf(b.x);
    o.w = ((unsigned int)f2bf(b.w) << 16) | f2bf(b.z);
    ((uint4*)dst)[i] = o;
  }
}

// ---------------- MFMA projection ----------------
// out[n][c] = sum_k h[n][k] * W[c][k] + b[c], scaled; stored bf16 head-major:
// pos = n*128 + (c%8)*16 + c/8   (c%8 = head, c/8 = dim)
// grid.x = ceil(N/64), grid.y = 3 (q,k,v). block = 256 (4 waves, 16 rows each).
__global__ __launch_bounds__(256) void proj_mfma(
    const unsigned short* __restrict__ hb, const unsigned short* __restrict__ wb,
    const float* __restrict__ bq, const float* __restrict__ bk,
    const float* __restrict__ bv,
    unsigned short* __restrict__ qkv, int n) {
  const int y = blockIdx.y;
  const unsigned short* W = wb + (size_t)y * HID * HID;
  const float* bias = (y == 0) ? bq : (y == 1) ? bk : bv;
  unsigned short* out = qkv + (size_t)y * n * HID;
  const float scale = (y == 0) ? 0.25f : 1.0f;  // q: DH^-0.5

  const int lane = threadIdx.x & 63;
  const int wave = threadIdx.x >> 6;
  const int n0 = blockIdx.x * 64 + wave * 16;

  int arow = n0 + (lane & 15);
  if (arow > n - 1) arow = n - 1;
  const int koff = (lane >> 4) * 8;  // k-block offset within fragment

  // A fragments: 4 K-steps of 32, lane holds 8 contiguous bf16
  short8 a0 = *(const short8*)(hb + (size_t)arow * HID +  0 + koff);
  short8 a1 = *(const short8*)(hb + (size_t)arow * HID + 32 + koff);
  short8 a2 = *(const short8*)(hb + (size_t)arow * HID + 64 + koff);
  short8 a3 = *(const short8*)(hb + (size_t)arow * HID + 96 + koff);

#pragma unroll
  for (int ct = 0; ct < 8; ++ct) {
    const int c = ct * 16 + (lane & 15);
    const unsigned short* wr = W + (size_t)c * HID + koff;
    f32x4 acc = {0.f, 0.f, 0.f, 0.f};
    acc = __builtin_amdgcn_mfma_f32_16x16x32_bf16(a0, *(const short8*)(wr +  0), acc, 0, 0, 0);
    acc = __builtin_amdgcn_mfma_f32_16x16x32_bf16(a1, *(const short8*)(wr + 32), acc, 0, 0, 0);
    acc = __builtin_amdgcn_mfma_f32_16x16x32_bf16(a2, *(const short8*)(wr + 64), acc, 0, 0, 0);
    acc = __builtin_amdgcn_mfma_f32_16x16x32_bf16(a3, *(const short8*)(wr + 96), acc, 0, 0, 0);

    const float bb = bias[c];
    const int cp = (c & 7) * 16 + (c >> 3);  // head-major position within row
#pragma unroll
    for (int r = 0; r < 4; ++r) {
      int row = n0 + (lane >> 4) * 4 + r;
      if (row < n)
        out[(size_t)row * HID + cp] = f2bf((acc[r] + bb) * scale);
    }
  }
}

// ---------------- CSR build ----------------
__global__ void hist_kernel(const int* __restrict__ src, int* __restrict__ deg, int e) {
  int i = blockIdx.x * blockDim.x + threadIdx.x;
  if (i < e) atomicAdd(&deg[src[i]], 1);
}

__global__ void scan_kernel(const int* __restrict__ deg, int* __restrict__ rowptr, int n) {
  __shared__ int part[1024];
  int t = threadIdx.x;
  int ch = (n + 1023) / 1024;
  int base = t * ch;
  int s = 0;
  for (int i = 0; i < ch; ++i) {
    int idx = base + i;
    if (idx < n) s += deg[idx];
  }
  part[t] = s;
  __syncthreads();
  for (int off = 1; off < 1024; off <<= 1) {
    int v = (t >= off) ? part[t - off] : 0;
    __syncthreads();
    part[t] += v;
    __syncthreads();
  }
  int excl = part[t] - s;
  for (int i = 0; i < ch; ++i) {
    int idx = base + i;
    if (idx < n) { rowptr[idx] = excl; excl += deg[idx]; }
  }
  if (t == 1023) rowptr[n] = part[1023];
}

__global__ void scatter_kernel(const int* __restrict__ src, const int* __restrict__ dst,
                               const float* __restrict__ val,
                               const int* __restrict__ rowptr, int* __restrict__ cursor,
                               int* __restrict__ csr_dst, float* __restrict__ csr_val, int e) {
  int i = blockIdx.x * blockDim.x + threadIdx.x;
  if (i < e) {
    int s = src[i];
    int p = atomicAdd(&cursor[s], 1);
    int idx = rowptr[s] + p;
    csr_dst[idx] = dst[i];
    csr_val[idx] = val[i];
  }
}

// ---------------- per-node online-softmax attention (bf16 head-major) -----
// one wave per node; lane l: head = l>>3, dims 2*(l&7), 2*(l&7)+1.
// k/v row read = one dword per lane at byte offset 4*l -> fully coalesced 256B.
__global__ __launch_bounds__(256) void node_kernel(
    const unsigned short* __restrict__ qb, const unsigned short* __restrict__ kb,
    const unsigned short* __restrict__ vb,
    const int* __restrict__ rowptr, const int* __restrict__ csr_dst,
    const float* __restrict__ csr_val,
    float* __restrict__ out, int n) {
  int wid = (blockIdx.x * blockDim.x + threadIdx.x) >> 6;
  int lane = threadIdx.x & 63;
  if (wid >= n) return;

  unsigned int qp = *(const unsigned int*)(qb + (size_t)wid * HID + 2 * lane);
  float q0 = bf2f((unsigned short)(qp & 0xFFFF));
  float q1 = bf2f((unsigned short)(qp >> 16));

  int beg = rowptr[wid], end = rowptr[wid + 1];
  float m = -INFINITY, s = 0.f, o0 = 0.f, o1 = 0.f;

  int d = 0; float vale = 0.f;
  if (beg < end) { d = csr_dst[beg]; vale = csr_val[beg]; }

  for (int i = beg; i < end; ++i) {
    unsigned int kp = *(const unsigned int*)(kb + (size_t)d * HID + 2 * lane);
    unsigned int vp = *(const unsigned int*)(vb + (size_t)d * HID + 2 * lane);
    // prefetch next edge's index/val while this edge's rows are in flight
    int dn = d; float valn = vale;
    if (i + 1 < end) { dn = csr_dst[i + 1]; valn = csr_val[i + 1]; }

    float k0 = bf2f((unsigned short)(kp & 0xFFFF));
    float k1 = bf2f((unsigned short)(kp >> 16));
    float v0 = bf2f((unsigned short)(vp & 0xFFFF));
    float v1 = bf2f((unsigned short)(vp >> 16));

    float p = q0 * k0 + q1 * k1;
    p += __shfl_xor(p, 1);
    p += __shfl_xor(p, 2);
    p += __shfl_xor(p, 4);       // per-head dot (8 lanes/head)
    float score = p * vale;

    float mn = fmaxf(m, score);
    float c = __expf(m - mn);    // first iter: exp(-inf)=0
    float w = __expf(score - mn);
    s = s * c + w;
    o0 = o0 * c + w * v0;
    o1 = o1 * c + w * v1;
    m = mn;

    d = dn; vale = valn;
  }

  float inv = (s > 0.f) ? 1.f / s : 0.f;
  int j = lane & 7, head = lane >> 3;
  int f0 = 16 * j + head;        // feature index d*8+head, d = 2j
  out[(size_t)wid * HID + f0] = o0 * inv;
  out[(size_t)wid * HID + f0 + 8] = o1 * inv;
}

// ---------------- launcher ----------------
extern "C" void kernel_launch(void* const* d_in, const int* in_sizes, int n_in,
                              void* d_out, int out_size, void* d_ws, size_t ws_size,
                              hipStream_t stream) {
  const float* h  = (const float*)d_in[0];
  const float* val = (const float*)d_in[1];
  const float* Wq = (const float*)d_in[2];
  const float* bq = (const float*)d_in[3];
  const float* Wk = (const float*)d_in[4];
  const float* bk = (const float*)d_in[5];
  const float* Wv = (const float*)d_in[6];
  const float* bv = (const float*)d_in[7];
  const int* src  = (const int*)d_in[8];
  const int* dst  = (const int*)d_in[9];

  int N = in_sizes[0] / HID;
  int E = in_sizes[8];
  float* out = (float*)d_out;

  // workspace layout (bf16 = unsigned short)
  unsigned short* hb  = (unsigned short*)d_ws;              // N*128
  unsigned short* wb  = hb + (size_t)N * HID;               // 3*128*128
  unsigned short* qkv = wb + 3 * HID * HID;                 // 3*N*128
  int* rowptr  = (int*)(qkv + (size_t)3 * N * HID);         // N+1
  int* deg     = rowptr + (N + 1);                          // N
  int* cursor  = deg + N;                                   // N
  int* csr_dst = cursor + N;                                // E
  float* csr_val = (float*)(csr_dst + E);                   // E

  unsigned short* qb = qkv;
  unsigned short* kb = qkv + (size_t)N * HID;
  unsigned short* vb = qkv + (size_t)2 * N * HID;

  hipMemsetAsync(deg, 0, sizeof(int) * 2 * (size_t)N, stream);  // deg + cursor

  // conversions
  int n8_h = N * HID / 8;
  convert_kernel<<<(n8_h + 255) / 256, 256, 0, stream>>>(h, hb, n8_h);
  int n8_w = HID * HID / 8;
  convert_kernel<<<(n8_w + 255) / 256, 256, 0, stream>>>(Wq, wb, n8_w);
  convert_kernel<<<(n8_w + 255) / 256, 256, 0, stream>>>(Wk, wb + HID * HID, n8_w);
  convert_kernel<<<(n8_w + 255) / 256, 256, 0, stream>>>(Wv, wb + 2 * HID * HID, n8_w);

  proj_mfma<<<dim3((N + 63) / 64, 3), 256, 0, stream>>>(hb, wb, bq, bk, bv, qkv, N);

  hist_kernel<<<(E + 255) / 256, 256, 0, stream>>>(src, deg, E);
  scan_kernel<<<1, 1024, 0, stream>>>(deg, rowptr, N);
  scatter_kernel<<<(E + 255) / 256, 256, 0, stream>>>(
      src, dst, val, rowptr, cursor, csr_dst, csr_val, E);
  node_kernel<<<(N + 3) / 4, 256, 0, stream>>>(
      qb, kb, vb, rowptr, csr_dst, csr_val, out, N);
}

// Round 4
// 259.660 us; speedup vs baseline: 1.9581x; 1.3079x over previous
//
#include <hip/hip_runtime.h>
#include <hip/hip_bf16.h>
#include <math.h>

#define HID 128
#define NH  8
#define SCHUNK 512  // elements per scan block

typedef __attribute__((ext_vector_type(8))) short short8;
typedef __attribute__((ext_vector_type(4))) float f32x4;

static __device__ __forceinline__ float bf2f(unsigned short u) {
  union { unsigned int i; float f; } c; c.i = ((unsigned int)u) << 16; return c.f;
}
static __device__ __forceinline__ unsigned short f2bf(float f) {
  union { float f; unsigned int i; } c; c.f = f;
  unsigned int r = c.i + 0x7FFFu + ((c.i >> 16) & 1u);  // round-nearest-even
  return (unsigned short)(r >> 16);
}

// ---------------- fp32 -> bf16 conversion (grid-stride, 8 elems/thread) ----
__global__ void convert_kernel(const float* __restrict__ src,
                               unsigned short* __restrict__ dst, int n8) {
  int stride = gridDim.x * blockDim.x;
  for (int i = blockIdx.x * blockDim.x + threadIdx.x; i < n8; i += stride) {
    float4 a = ((const float4*)src)[2 * i];
    float4 b = ((const float4*)src)[2 * i + 1];
    uint4 o;
    o.x = ((unsigned int)f2bf(a.y) << 16) | f2bf(a.x);
    o.y = ((unsigned int)f2bf(a.w) << 16) | f2bf(a.z);
    o.z = ((unsigned int)f2bf(b.y) << 16) | f2bf(b.x);
    o.w = ((unsigned int)f2bf(b.w) << 16) | f2bf(b.z);
    ((uint4*)dst)[i] = o;
  }
}

// ---------------- MFMA projection ----------------
// out[n][c] = sum_k h[n][k] * W[c][k] + b[c], scaled; stored bf16 head-major:
// pos = n*128 + (c%8)*16 + c/8   (c%8 = head, c/8 = dim)
__global__ __launch_bounds__(256) void proj_mfma(
    const unsigned short* __restrict__ hb, const unsigned short* __restrict__ wb,
    const float* __restrict__ bq, const float* __restrict__ bk,
    const float* __restrict__ bv,
    unsigned short* __restrict__ qkv, int n) {
  const int y = blockIdx.y;
  const unsigned short* W = wb + (size_t)y * HID * HID;
  const float* bias = (y == 0) ? bq : (y == 1) ? bk : bv;
  unsigned short* out = qkv + (size_t)y * n * HID;
  const float scale = (y == 0) ? 0.25f : 1.0f;  // q: DH^-0.5

  const int lane = threadIdx.x & 63;
  const int wave = threadIdx.x >> 6;
  const int n0 = blockIdx.x * 64 + wave * 16;

  int arow = n0 + (lane & 15);
  if (arow > n - 1) arow = n - 1;
  const int koff = (lane >> 4) * 8;

  short8 a0 = *(const short8*)(hb + (size_t)arow * HID +  0 + koff);
  short8 a1 = *(const short8*)(hb + (size_t)arow * HID + 32 + koff);
  short8 a2 = *(const short8*)(hb + (size_t)arow * HID + 64 + koff);
  short8 a3 = *(const short8*)(hb + (size_t)arow * HID + 96 + koff);

#pragma unroll
  for (int ct = 0; ct < 8; ++ct) {
    const int c = ct * 16 + (lane & 15);
    const unsigned short* wr = W + (size_t)c * HID + koff;
    f32x4 acc = {0.f, 0.f, 0.f, 0.f};
    acc = __builtin_amdgcn_mfma_f32_16x16x32_bf16(a0, *(const short8*)(wr +  0), acc, 0, 0, 0);
    acc = __builtin_amdgcn_mfma_f32_16x16x32_bf16(a1, *(const short8*)(wr + 32), acc, 0, 0, 0);
    acc = __builtin_amdgcn_mfma_f32_16x16x32_bf16(a2, *(const short8*)(wr + 64), acc, 0, 0, 0);
    acc = __builtin_amdgcn_mfma_f32_16x16x32_bf16(a3, *(const short8*)(wr + 96), acc, 0, 0, 0);

    const float bb = bias[c];
    const int cp = (c & 7) * 16 + (c >> 3);
#pragma unroll
    for (int r = 0; r < 4; ++r) {
      int row = n0 + (lane >> 4) * 4 + r;
      if (row < n)
        out[(size_t)row * HID + cp] = f2bf((acc[r] + bb) * scale);
    }
  }
}

// ---------------- CSR build ----------------
__global__ void hist_kernel(const int* __restrict__ src, int* __restrict__ deg, int e) {
  int i = blockIdx.x * blockDim.x + threadIdx.x;
  if (i < e) atomicAdd(&deg[src[i]], 1);
}

// --- hierarchical scan: reduce -> scan partials -> per-block scan ---
__global__ __launch_bounds__(256) void reduce_blocks(
    const int* __restrict__ deg, int* __restrict__ partials, int n) {
  __shared__ int sm[256];
  int base = blockIdx.x * SCHUNK;
  int t = threadIdx.x;
  int i0 = base + t, i1 = base + t + 256;
  int s = ((i0 < n) ? deg[i0] : 0) + ((i1 < n) ? deg[i1] : 0);
  sm[t] = s;
  __syncthreads();
  for (int off = 128; off > 0; off >>= 1) {
    if (t < off) sm[t] += sm[t + off];
    __syncthreads();
  }
  if (t == 0) partials[blockIdx.x] = sm[0];
}

__global__ __launch_bounds__(1024) void scan_partials(
    const int* __restrict__ partials, int* __restrict__ blockoff,
    int* __restrict__ rowptr, int nb, int n) {
  __shared__ int sm[1024];
  int t = threadIdx.x;
  int v = (t < nb) ? partials[t] : 0;
  sm[t] = v;
  __syncthreads();
  for (int off = 1; off < 1024; off <<= 1) {
    int u = (t >= off) ? sm[t - off] : 0;
    __syncthreads();
    sm[t] += u;
    __syncthreads();
  }
  if (t < nb) blockoff[t] = sm[t] - v;   // exclusive
  if (t == 1023) rowptr[n] = sm[1023];   // total = E
}

__global__ __launch_bounds__(256) void scan_blocks(
    const int* __restrict__ deg, const int* __restrict__ blockoff,
    int* __restrict__ rowptr, int n) {
  int base = blockIdx.x * SCHUNK;
  int t = threadIdx.x;
  int lane = t & 63, wave = t >> 6;
  int i0 = base + 2 * t, i1 = i0 + 1;
  int d0 = (i0 < n) ? deg[i0] : 0;
  int d1 = (i1 < n) ? deg[i1] : 0;
  int s = d0 + d1;
  int incl = s;
#pragma unroll
  for (int off = 1; off < 64; off <<= 1) {
    int u = __shfl_up(incl, off);
    if (lane >= off) incl += u;
  }
  __shared__ int wsum[4];
  if (lane == 63) wsum[wave] = incl;
  __syncthreads();
  int woff = 0;
  for (int w = 0; w < wave; ++w) woff += wsum[w];
  int excl = woff + (incl - s) + blockoff[blockIdx.x];
  if (i0 < n) rowptr[i0] = excl;
  if (i1 < n) rowptr[i1] = excl + d0;
}

__global__ void scatter_kernel(const int* __restrict__ src, const int* __restrict__ dst,
                               const float* __restrict__ val,
                               const int* __restrict__ rowptr, int* __restrict__ cursor,
                               int* __restrict__ csr_dst, float* __restrict__ csr_val, int e) {
  int i = blockIdx.x * blockDim.x + threadIdx.x;
  if (i < e) {
    int s = src[i];
    int p = atomicAdd(&cursor[s], 1);
    int idx = rowptr[s] + p;
    csr_dst[idx] = dst[i];
    csr_val[idx] = val[i];
  }
}

// ---------------- per-node online-softmax attention (bf16 head-major) -----
// one wave per node; lane l: head = l>>3, dims 2*(l&7), 2*(l&7)+1.
__global__ __launch_bounds__(256) void node_kernel(
    const unsigned short* __restrict__ qb, const unsigned short* __restrict__ kb,
    const unsigned short* __restrict__ vb,
    const int* __restrict__ rowptr, const int* __restrict__ csr_dst,
    const float* __restrict__ csr_val,
    float* __restrict__ out, int n) {
  int wid = (blockIdx.x * blockDim.x + threadIdx.x) >> 6;
  int lane = threadIdx.x & 63;
  if (wid >= n) return;

  unsigned int qp = *(const unsigned int*)(qb + (size_t)wid * HID + 2 * lane);
  float q0 = bf2f((unsigned short)(qp & 0xFFFF));
  float q1 = bf2f((unsigned short)(qp >> 16));

  int beg = rowptr[wid], end = rowptr[wid + 1];
  float m = -INFINITY, s = 0.f, o0 = 0.f, o1 = 0.f;

  int d = 0; float vale = 0.f;
  if (beg < end) { d = csr_dst[beg]; vale = csr_val[beg]; }

  for (int i = beg; i < end; ++i) {
    unsigned int kp = *(const unsigned int*)(kb + (size_t)d * HID + 2 * lane);
    unsigned int vp = *(const unsigned int*)(vb + (size_t)d * HID + 2 * lane);
    int dn = d; float valn = vale;
    if (i + 1 < end) { dn = csr_dst[i + 1]; valn = csr_val[i + 1]; }

    float k0 = bf2f((unsigned short)(kp & 0xFFFF));
    float k1 = bf2f((unsigned short)(kp >> 16));
    float v0 = bf2f((unsigned short)(vp & 0xFFFF));
    float v1 = bf2f((unsigned short)(vp >> 16));

    float p = q0 * k0 + q1 * k1;
    p += __shfl_xor(p, 1);
    p += __shfl_xor(p, 2);
    p += __shfl_xor(p, 4);       // per-head dot (8 lanes/head)
    float score = p * vale;

    float mn = fmaxf(m, score);
    float c = __expf(m - mn);    // first iter: exp(-inf)=0
    float w = __expf(score - mn);
    s = s * c + w;
    o0 = o0 * c + w * v0;
    o1 = o1 * c + w * v1;
    m = mn;

    d = dn; vale = valn;
  }

  float inv = (s > 0.f) ? 1.f / s : 0.f;
  int j = lane & 7, head = lane >> 3;
  int f0 = 16 * j + head;
  out[(size_t)wid * HID + f0] = o0 * inv;
  out[(size_t)wid * HID + f0 + 8] = o1 * inv;
}

// ---------------- launcher ----------------
extern "C" void kernel_launch(void* const* d_in, const int* in_sizes, int n_in,
                              void* d_out, int out_size, void* d_ws, size_t ws_size,
                              hipStream_t stream) {
  const float* h  = (const float*)d_in[0];
  const float* val = (const float*)d_in[1];
  const float* Wq = (const float*)d_in[2];
  const float* bq = (const float*)d_in[3];
  const float* Wk = (const float*)d_in[4];
  const float* bk = (const float*)d_in[5];
  const float* Wv = (const float*)d_in[6];
  const float* bv = (const float*)d_in[7];
  const int* src  = (const int*)d_in[8];
  const int* dst  = (const int*)d_in[9];

  int N = in_sizes[0] / HID;
  int E = in_sizes[8];
  float* out = (float*)d_out;
  int nb = (N + SCHUNK - 1) / SCHUNK;

  // workspace layout (bf16 = unsigned short)
  unsigned short* hb  = (unsigned short*)d_ws;              // N*128
  unsigned short* wb  = hb + (size_t)N * HID;               // 3*128*128
  unsigned short* qkv = wb + 3 * HID * HID;                 // 3*N*128
  int* rowptr  = (int*)(qkv + (size_t)3 * N * HID);         // N+1
  int* deg     = rowptr + (N + 1);                          // N
  int* cursor  = deg + N;                                   // N
  int* partials = cursor + N;                               // nb
  int* blockoff = partials + nb;                            // nb
  int* csr_dst = blockoff + nb;                             // E
  float* csr_val = (float*)(csr_dst + E);                   // E

  unsigned short* qb = qkv;
  unsigned short* kb = qkv + (size_t)N * HID;
  unsigned short* vb = qkv + (size_t)2 * N * HID;

  hipMemsetAsync(deg, 0, sizeof(int) * 2 * (size_t)N, stream);  // deg + cursor

  // conversions
  int n8_h = N * HID / 8;
  convert_kernel<<<(n8_h + 255) / 256, 256, 0, stream>>>(h, hb, n8_h);
  int n8_w = HID * HID / 8;
  convert_kernel<<<(n8_w + 255) / 256, 256, 0, stream>>>(Wq, wb, n8_w);
  convert_kernel<<<(n8_w + 255) / 256, 256, 0, stream>>>(Wk, wb + HID * HID, n8_w);
  convert_kernel<<<(n8_w + 255) / 256, 256, 0, stream>>>(Wv, wb + 2 * HID * HID, n8_w);

  proj_mfma<<<dim3((N + 63) / 64, 3), 256, 0, stream>>>(hb, wb, bq, bk, bv, qkv, N);

  hist_kernel<<<(E + 255) / 256, 256, 0, stream>>>(src, deg, E);
  reduce_blocks<<<nb, 256, 0, stream>>>(deg, partials, N);
  scan_partials<<<1, 1024, 0, stream>>>(partials, blockoff, rowptr, nb, N);
  scan_blocks<<<nb, 256, 0, stream>>>(deg, blockoff, rowptr, N);
  scatter_kernel<<<(E + 255) / 256, 256, 0, stream>>>(
      src, dst, val, rowptr, cursor, csr_dst, csr_val, E);
  node_kernel<<<(N + 3) / 4, 256, 0, stream>>>(
      qb, kb, vb, rowptr, csr_dst, csr_val, out, N);
}

// Round 5
// 240.837 us; speedup vs baseline: 2.1111x; 1.0782x over previous
//
#include <hip/hip_runtime.h>
#include <hip/hip_bf16.h>
#include <math.h>

#define HID 128
#define NH  8
#define SCHUNK 512  // elements per scan block

typedef __attribute__((ext_vector_type(8))) short short8;
typedef __attribute__((ext_vector_type(4))) float f32x4;

static __device__ __forceinline__ float bf2f(unsigned short u) {
  union { unsigned int i; float f; } c; c.i = ((unsigned int)u) << 16; return c.f;
}
static __device__ __forceinline__ float blo(unsigned int u) {
  union { unsigned int i; float f; } c; c.i = u << 16; return c.f;
}
static __device__ __forceinline__ float bhi(unsigned int u) {
  union { unsigned int i; float f; } c; c.i = u & 0xFFFF0000u; return c.f;
}
static __device__ __forceinline__ unsigned short f2bf(float f) {
  union { float f; unsigned int i; } c; c.f = f;
  unsigned int r = c.i + 0x7FFFu + ((c.i >> 16) & 1u);  // round-nearest-even
  return (unsigned short)(r >> 16);
}

// ---------------- fp32 -> bf16 conversion (grid-stride, 8 elems/thread) ----
__global__ void convert_kernel(const float* __restrict__ src,
                               unsigned short* __restrict__ dst, int n8) {
  int stride = gridDim.x * blockDim.x;
  for (int i = blockIdx.x * blockDim.x + threadIdx.x; i < n8; i += stride) {
    float4 a = ((const float4*)src)[2 * i];
    float4 b = ((const float4*)src)[2 * i + 1];
    uint4 o;
    o.x = ((unsigned int)f2bf(a.y) << 16) | f2bf(a.x);
    o.y = ((unsigned int)f2bf(a.w) << 16) | f2bf(a.z);
    o.z = ((unsigned int)f2bf(b.y) << 16) | f2bf(b.x);
    o.w = ((unsigned int)f2bf(b.w) << 16) | f2bf(b.z);
    ((uint4*)dst)[i] = o;
  }
}

// convert 3 weight matrices in one launch (blockIdx.y picks the matrix)
__global__ void convert3_kernel(const float* __restrict__ s0, const float* __restrict__ s1,
                                const float* __restrict__ s2,
                                unsigned short* __restrict__ dst, int n8) {
  const float* s = (blockIdx.y == 0) ? s0 : (blockIdx.y == 1) ? s1 : s2;
  unsigned short* d = dst + (size_t)blockIdx.y * n8 * 8;
  for (int i = blockIdx.x * blockDim.x + threadIdx.x; i < n8;
       i += gridDim.x * blockDim.x) {
    float4 a = ((const float4*)s)[2 * i];
    float4 b = ((const float4*)s)[2 * i + 1];
    uint4 o;
    o.x = ((unsigned int)f2bf(a.y) << 16) | f2bf(a.x);
    o.y = ((unsigned int)f2bf(a.w) << 16) | f2bf(a.z);
    o.z = ((unsigned int)f2bf(b.y) << 16) | f2bf(b.x);
    o.w = ((unsigned int)f2bf(b.w) << 16) | f2bf(b.z);
    ((uint4*)d)[i] = o;
  }
}

// ---------------- MFMA projection ----------------
// out feature c -> head-major pos cp = (c%8)*16 + c/8  ([head][dim], 16 dims
// contiguous per head). q goes to qb[node][128]; k/v interleave into
// kvb[node][256] = [k(128) | v(128)] so one edge gather touches one 512B record.
__global__ __launch_bounds__(256) void proj_mfma(
    const unsigned short* __restrict__ hb, const unsigned short* __restrict__ wb,
    const float* __restrict__ bq, const float* __restrict__ bk,
    const float* __restrict__ bv,
    unsigned short* __restrict__ qb, unsigned short* __restrict__ kvb, int n) {
  const int y = blockIdx.y;
  const unsigned short* W = wb + (size_t)y * HID * HID;
  const float* bias = (y == 0) ? bq : (y == 1) ? bk : bv;
  const float scale = (y == 0) ? 0.25f : 1.0f;  // q: DH^-0.5

  unsigned short* out;
  int ostride;
  if (y == 0)      { out = qb;        ostride = HID; }
  else if (y == 1) { out = kvb;       ostride = 2 * HID; }
  else             { out = kvb + HID; ostride = 2 * HID; }

  const int lane = threadIdx.x & 63;
  const int wave = threadIdx.x >> 6;
  const int n0 = blockIdx.x * 64 + wave * 16;

  int arow = n0 + (lane & 15);
  if (arow > n - 1) arow = n - 1;
  const int koff = (lane >> 4) * 8;

  short8 a0 = *(const short8*)(hb + (size_t)arow * HID +  0 + koff);
  short8 a1 = *(const short8*)(hb + (size_t)arow * HID + 32 + koff);
  short8 a2 = *(const short8*)(hb + (size_t)arow * HID + 64 + koff);
  short8 a3 = *(const short8*)(hb + (size_t)arow * HID + 96 + koff);

#pragma unroll
  for (int ct = 0; ct < 8; ++ct) {
    const int c = ct * 16 + (lane & 15);
    const unsigned short* wr = W + (size_t)c * HID + koff;
    f32x4 acc = {0.f, 0.f, 0.f, 0.f};
    acc = __builtin_amdgcn_mfma_f32_16x16x32_bf16(a0, *(const short8*)(wr +  0), acc, 0, 0, 0);
    acc = __builtin_amdgcn_mfma_f32_16x16x32_bf16(a1, *(const short8*)(wr + 32), acc, 0, 0, 0);
    acc = __builtin_amdgcn_mfma_f32_16x16x32_bf16(a2, *(const short8*)(wr + 64), acc, 0, 0, 0);
    acc = __builtin_amdgcn_mfma_f32_16x16x32_bf16(a3, *(const short8*)(wr + 96), acc, 0, 0, 0);

    const float bb = bias[c];
    const int cp = (c & 7) * 16 + (c >> 3);
#pragma unroll
    for (int r = 0; r < 4; ++r) {
      int row = n0 + (lane >> 4) * 4 + r;
      if (row < n)
        out[(size_t)row * ostride + cp] = f2bf((acc[r] + bb) * scale);
    }
  }
}

// ---------------- CSR build ----------------
__global__ void hist_kernel(const int* __restrict__ src, int* __restrict__ deg, int e) {
  int i = blockIdx.x * blockDim.x + threadIdx.x;
  if (i < e) atomicAdd(&deg[src[i]], 1);
}

__global__ __launch_bounds__(256) void reduce_blocks(
    const int* __restrict__ deg, int* __restrict__ partials, int n) {
  __shared__ int sm[256];
  int base = blockIdx.x * SCHUNK;
  int t = threadIdx.x;
  int i0 = base + t, i1 = base + t + 256;
  int s = ((i0 < n) ? deg[i0] : 0) + ((i1 < n) ? deg[i1] : 0);
  sm[t] = s;
  __syncthreads();
  for (int off = 128; off > 0; off >>= 1) {
    if (t < off) sm[t] += sm[t + off];
    __syncthreads();
  }
  if (t == 0) partials[blockIdx.x] = sm[0];
}

__global__ __launch_bounds__(1024) void scan_partials(
    const int* __restrict__ partials, int* __restrict__ blockoff,
    int* __restrict__ rowptr, int nb, int n) {
  __shared__ int sm[1024];
  int t = threadIdx.x;
  int v = (t < nb) ? partials[t] : 0;
  sm[t] = v;
  __syncthreads();
  for (int off = 1; off < 1024; off <<= 1) {
    int u = (t >= off) ? sm[t - off] : 0;
    __syncthreads();
    sm[t] += u;
    __syncthreads();
  }
  if (t < nb) blockoff[t] = sm[t] - v;   // exclusive
  if (t == 1023) rowptr[n] = sm[1023];   // total = E
}

__global__ __launch_bounds__(256) void scan_blocks(
    const int* __restrict__ deg, const int* __restrict__ blockoff,
    int* __restrict__ rowptr, int n) {
  int base = blockIdx.x * SCHUNK;
  int t = threadIdx.x;
  int lane = t & 63, wave = t >> 6;
  int i0 = base + 2 * t, i1 = i0 + 1;
  int d0 = (i0 < n) ? deg[i0] : 0;
  int d1 = (i1 < n) ? deg[i1] : 0;
  int s = d0 + d1;
  int incl = s;
#pragma unroll
  for (int off = 1; off < 64; off <<= 1) {
    int u = __shfl_up(incl, off);
    if (lane >= off) incl += u;
  }
  __shared__ int wsum[4];
  if (lane == 63) wsum[wave] = incl;
  __syncthreads();
  int woff = 0;
  for (int w = 0; w < wave; ++w) woff += wsum[w];
  int excl = woff + (incl - s) + blockoff[blockIdx.x];
  if (i0 < n) rowptr[i0] = excl;
  if (i1 < n) rowptr[i1] = excl + d0;
}

__global__ void scatter_kernel(const int* __restrict__ src, const int* __restrict__ dst,
                               const float* __restrict__ val,
                               const int* __restrict__ rowptr, int* __restrict__ cursor,
                               int* __restrict__ csr_dst, float* __restrict__ csr_val, int e) {
  int i = blockIdx.x * blockDim.x + threadIdx.x;
  if (i < e) {
    int s = src[i];
    int p = atomicAdd(&cursor[s], 1);
    int idx = rowptr[s] + p;
    csr_dst[idx] = dst[i];
    csr_val[idx] = val[i];
  }
}

// ---------------- per-node attention: lane = (edge-slot, head) -------------
// wave per node: eg = lane>>3 (8 edge slots), head = lane&7.
// Lane does the FULL 16-dim dot for its (edge, head) in-register; per chunk
// of 8 edges one 3-shfl max all-reduce + defer-max (T13, THR=8) rescale.
__global__ __launch_bounds__(256) void node_kernel(
    const unsigned short* __restrict__ qb, const unsigned short* __restrict__ kvb,
    const int* __restrict__ rowptr, const int* __restrict__ csr_dst,
    const float* __restrict__ csr_val,
    float* __restrict__ out, int n) {
  int wid = (blockIdx.x * blockDim.x + threadIdx.x) >> 6;
  int lane = threadIdx.x & 63;
  if (wid >= n) return;
  const int head = lane & 7;
  const int eg = lane >> 3;

  // q[head][0..15] -> 16 f32 (scaled already)
  const uint4* qr = (const uint4*)(qb + (size_t)wid * HID + head * 16);
  uint4 q0 = qr[0], q1 = qr[1];
  float qf[16];
  {
    unsigned int qd[8] = {q0.x, q0.y, q0.z, q0.w, q1.x, q1.y, q1.z, q1.w};
#pragma unroll
    for (int j = 0; j < 8; ++j) { qf[2 * j] = blo(qd[j]); qf[2 * j + 1] = bhi(qd[j]); }
  }

  int beg = rowptr[wid], end = rowptr[wid + 1];
  float m = -INFINITY, s = 0.f;
  float o[16];
#pragma unroll
  for (int j = 0; j < 16; ++j) o[j] = 0.f;

  for (int base = beg; base < end; base += 8) {
    int i = base + eg;
    bool valid = i < end;
    int d = valid ? csr_dst[i] : 0;
    float vale = valid ? csr_val[i] : 0.f;

    const uint4* kr = (const uint4*)(kvb + (size_t)d * (2 * HID) + head * 16);
    uint4 ka = kr[0], kb2 = kr[1];     // k dims 0..15
    uint4 va = kr[16], vb2 = kr[17];   // v dims 0..15 (+128 shorts)

    float dot = 0.f;
    {
      unsigned int kd[8] = {ka.x, ka.y, ka.z, ka.w, kb2.x, kb2.y, kb2.z, kb2.w};
#pragma unroll
      for (int j = 0; j < 8; ++j)
        dot += qf[2 * j] * blo(kd[j]) + qf[2 * j + 1] * bhi(kd[j]);
    }
    float score = valid ? dot * vale : -INFINITY;

    // chunk max across the 8 edge slots (same head)
    float mx = score;
    mx = fmaxf(mx, __shfl_xor(mx, 8));
    mx = fmaxf(mx, __shfl_xor(mx, 16));
    mx = fmaxf(mx, __shfl_xor(mx, 32));

    if (!__all(mx <= m + 8.f)) {       // rare: rescale (wave-uniform branch)
      float mn = fmaxf(m, mx);
      float c = __expf(m - mn);        // first chunk: exp(-inf)=0 zeroes s,o
      s *= c;
#pragma unroll
      for (int j = 0; j < 16; ++j) o[j] *= c;
      m = mn;
    }

    float w = __expf(score - m);       // invalid: exp(-inf)=0
    s += w;
    {
      unsigned int vd[8] = {va.x, va.y, va.z, va.w, vb2.x, vb2.y, vb2.z, vb2.w};
#pragma unroll
      for (int j = 0; j < 8; ++j) {
        o[2 * j]     += w * blo(vd[j]);
        o[2 * j + 1] += w * bhi(vd[j]);
      }
    }
  }

  // merge the 8 edge-slot partials (m already common per head)
  s += __shfl_xor(s, 8); s += __shfl_xor(s, 16); s += __shfl_xor(s, 32);
#pragma unroll
  for (int j = 0; j < 16; ++j) {
    o[j] += __shfl_xor(o[j], 8);
    o[j] += __shfl_xor(o[j], 16);
    o[j] += __shfl_xor(o[j], 32);
  }

  float inv = (s > 0.f) ? 1.f / s : 0.f;
  // feature f = d*8 + head; distribute 16 stores: eg handles d = eg, eg+8
#pragma unroll
  for (int dd = 0; dd < 16; ++dd) {
    if (eg == (dd & 7))
      out[(size_t)wid * HID + dd * 8 + head] = o[dd] * inv;
  }
}

// ---------------- launcher ----------------
extern "C" void kernel_launch(void* const* d_in, const int* in_sizes, int n_in,
                              void* d_out, int out_size, void* d_ws, size_t ws_size,
                              hipStream_t stream) {
  const float* h  = (const float*)d_in[0];
  const float* val = (const float*)d_in[1];
  const float* Wq = (const float*)d_in[2];
  const float* bq = (const float*)d_in[3];
  const float* Wk = (const float*)d_in[4];
  const float* bk = (const float*)d_in[5];
  const float* Wv = (const float*)d_in[6];
  const float* bv = (const float*)d_in[7];
  const int* src  = (const int*)d_in[8];
  const int* dst  = (const int*)d_in[9];

  int N = in_sizes[0] / HID;
  int E = in_sizes[8];
  float* out = (float*)d_out;
  int nb = (N + SCHUNK - 1) / SCHUNK;

  // workspace layout (bf16 = unsigned short)
  unsigned short* hb  = (unsigned short*)d_ws;              // N*128
  unsigned short* wb  = hb + (size_t)N * HID;               // 3*128*128
  unsigned short* qb  = wb + 3 * HID * HID;                 // N*128
  unsigned short* kvb = qb + (size_t)N * HID;               // N*256
  int* rowptr  = (int*)(kvb + (size_t)2 * N * HID);         // N+1
  int* deg     = rowptr + (N + 1);                          // N
  int* cursor  = deg + N;                                   // N
  int* partials = cursor + N;                               // nb
  int* blockoff = partials + nb;                            // nb
  int* csr_dst = blockoff + nb;                             // E
  float* csr_val = (float*)(csr_dst + E);                   // E

  hipMemsetAsync(deg, 0, sizeof(int) * 2 * (size_t)N, stream);  // deg + cursor

  int n8_h = N * HID / 8;
  convert_kernel<<<(n8_h + 255) / 256, 256, 0, stream>>>(h, hb, n8_h);
  int n8_w = HID * HID / 8;
  convert3_kernel<<<dim3((n8_w + 255) / 256, 3), 256, 0, stream>>>(Wq, Wk, Wv, wb, n8_w);

  proj_mfma<<<dim3((N + 63) / 64, 3), 256, 0, stream>>>(hb, wb, bq, bk, bv, qb, kvb, N);

  hist_kernel<<<(E + 255) / 256, 256, 0, stream>>>(src, deg, E);
  reduce_blocks<<<nb, 256, 0, stream>>>(deg, partials, N);
  scan_partials<<<1, 1024, 0, stream>>>(partials, blockoff, rowptr, nb, N);
  scan_blocks<<<nb, 256, 0, stream>>>(deg, blockoff, rowptr, N);
  scatter_kernel<<<(E + 255) / 256, 256, 0, stream>>>(
      src, dst, val, rowptr, cursor, csr_dst, csr_val, E);
  node_kernel<<<(N + 3) / 4, 256, 0, stream>>>(
      qb, kvb, rowptr, csr_dst, csr_val, out, N);
}

// Round 6
// 233.442 us; speedup vs baseline: 2.1780x; 1.0317x over previous
//
#include <hip/hip_runtime.h>
#include <hip/hip_bf16.h>
#include <math.h>

#define HID 128
#define NH  8
#define SCHUNK 512  // elements per scan block
#define TPAD 136    // 128 + 8 shorts: 272B row stride (16B-aligned, bank-shifted)

typedef __attribute__((ext_vector_type(8))) short short8;
typedef __attribute__((ext_vector_type(4))) float f32x4;

static __device__ __forceinline__ float blo(unsigned int u) {
  union { unsigned int i; float f; } c; c.i = u << 16; return c.f;
}
static __device__ __forceinline__ float bhi(unsigned int u) {
  union { unsigned int i; float f; } c; c.i = u & 0xFFFF0000u; return c.f;
}
static __device__ __forceinline__ unsigned short f2bf(float f) {
  union { float f; unsigned int i; } c; c.f = f;
  unsigned int r = c.i + 0x7FFFu + ((c.i >> 16) & 1u);  // round-nearest-even
  return (unsigned short)(r >> 16);
}

// ---------------- fp32 -> bf16 conversion (grid-stride, 8 elems/thread) ----
__global__ void convert_kernel(const float* __restrict__ src,
                               unsigned short* __restrict__ dst, int n8) {
  int stride = gridDim.x * blockDim.x;
  for (int i = blockIdx.x * blockDim.x + threadIdx.x; i < n8; i += stride) {
    float4 a = ((const float4*)src)[2 * i];
    float4 b = ((const float4*)src)[2 * i + 1];
    uint4 o;
    o.x = ((unsigned int)f2bf(a.y) << 16) | f2bf(a.x);
    o.y = ((unsigned int)f2bf(a.w) << 16) | f2bf(a.z);
    o.z = ((unsigned int)f2bf(b.y) << 16) | f2bf(b.x);
    o.w = ((unsigned int)f2bf(b.w) << 16) | f2bf(b.z);
    ((uint4*)dst)[i] = o;
  }
}

// convert 3 weight matrices in one launch (blockIdx.y picks the matrix)
__global__ void convert3_kernel(const float* __restrict__ s0, const float* __restrict__ s1,
                                const float* __restrict__ s2,
                                unsigned short* __restrict__ dst, int n8) {
  const float* s = (blockIdx.y == 0) ? s0 : (blockIdx.y == 1) ? s1 : s2;
  unsigned short* d = dst + (size_t)blockIdx.y * n8 * 8;
  for (int i = blockIdx.x * blockDim.x + threadIdx.x; i < n8;
       i += gridDim.x * blockDim.x) {
    float4 a = ((const float4*)s)[2 * i];
    float4 b = ((const float4*)s)[2 * i + 1];
    uint4 o;
    o.x = ((unsigned int)f2bf(a.y) << 16) | f2bf(a.x);
    o.y = ((unsigned int)f2bf(a.w) << 16) | f2bf(a.z);
    o.z = ((unsigned int)f2bf(b.y) << 16) | f2bf(b.x);
    o.w = ((unsigned int)f2bf(b.w) << 16) | f2bf(b.z);
    ((uint4*)d)[i] = o;
  }
}

// ---------------- MFMA projection (LDS-staged permuted store) ----------------
// out feature c -> head-major pos cp = (c%8)*16 + c/8. Permutation applied in
// a per-wave LDS tile; global writes are 16B coalesced (fixes the 6x write
// amplification from scattered 2B stores).
__global__ __launch_bounds__(256) void proj_mfma(
    const unsigned short* __restrict__ hb, const unsigned short* __restrict__ wb,
    const float* __restrict__ bq, const float* __restrict__ bk,
    const float* __restrict__ bv,
    unsigned short* __restrict__ qb, unsigned short* __restrict__ kvb, int n) {
  __shared__ unsigned short tile[4][16][TPAD];  // per-wave 16x128 (+pad)

  const int y = blockIdx.y;
  const unsigned short* W = wb + (size_t)y * HID * HID;
  const float* bias = (y == 0) ? bq : (y == 1) ? bk : bv;
  const float scale = (y == 0) ? 0.25f : 1.0f;  // q: DH^-0.5

  unsigned short* out;
  int ostride;
  if (y == 0)      { out = qb;        ostride = HID; }
  else if (y == 1) { out = kvb;       ostride = 2 * HID; }
  else             { out = kvb + HID; ostride = 2 * HID; }

  const int lane = threadIdx.x & 63;
  const int wave = threadIdx.x >> 6;
  const int n0 = blockIdx.x * 64 + wave * 16;

  int arow = n0 + (lane & 15);
  if (arow > n - 1) arow = n - 1;
  const int koff = (lane >> 4) * 8;

  short8 a0 = *(const short8*)(hb + (size_t)arow * HID +  0 + koff);
  short8 a1 = *(const short8*)(hb + (size_t)arow * HID + 32 + koff);
  short8 a2 = *(const short8*)(hb + (size_t)arow * HID + 64 + koff);
  short8 a3 = *(const short8*)(hb + (size_t)arow * HID + 96 + koff);

#pragma unroll
  for (int ct = 0; ct < 8; ++ct) {
    const int c = ct * 16 + (lane & 15);
    const unsigned short* wr = W + (size_t)c * HID + koff;
    f32x4 acc = {0.f, 0.f, 0.f, 0.f};
    acc = __builtin_amdgcn_mfma_f32_16x16x32_bf16(a0, *(const short8*)(wr +  0), acc, 0, 0, 0);
    acc = __builtin_amdgcn_mfma_f32_16x16x32_bf16(a1, *(const short8*)(wr + 32), acc, 0, 0, 0);
    acc = __builtin_amdgcn_mfma_f32_16x16x32_bf16(a2, *(const short8*)(wr + 64), acc, 0, 0, 0);
    acc = __builtin_amdgcn_mfma_f32_16x16x32_bf16(a3, *(const short8*)(wr + 96), acc, 0, 0, 0);

    const float bb = bias[c];
    const int cp = (c & 7) * 16 + (c >> 3);  // head-major position within row
#pragma unroll
    for (int r = 0; r < 4; ++r) {
      int rl = (lane >> 4) * 4 + r;          // local row 0..15
      tile[wave][rl][cp] = f2bf((acc[r] + bb) * scale);
    }
  }

  // coalesced write-out: 16 rows x 256B, 16 lanes cover one row per pass
#pragma unroll
  for (int p = 0; p < 4; ++p) {
    int rl = p * 4 + (lane >> 4);
    int row = n0 + rl;
    if (row < n) {
      uint4 vv = *(const uint4*)&tile[wave][rl][(lane & 15) * 8];
      *(uint4*)(out + (size_t)row * ostride + (lane & 15) * 8) = vv;
    }
  }
}

// ---------------- CSR build ----------------
__global__ void hist_kernel(const int* __restrict__ src, int* __restrict__ deg, int e) {
  int i = blockIdx.x * blockDim.x + threadIdx.x;
  if (i < e) atomicAdd(&deg[src[i]], 1);
}

__global__ __launch_bounds__(256) void reduce_blocks(
    const int* __restrict__ deg, int* __restrict__ partials, int n) {
  __shared__ int sm[256];
  int base = blockIdx.x * SCHUNK;
  int t = threadIdx.x;
  int i0 = base + t, i1 = base + t + 256;
  int s = ((i0 < n) ? deg[i0] : 0) + ((i1 < n) ? deg[i1] : 0);
  sm[t] = s;
  __syncthreads();
  for (int off = 128; off > 0; off >>= 1) {
    if (t < off) sm[t] += sm[t + off];
    __syncthreads();
  }
  if (t == 0) partials[blockIdx.x] = sm[0];
}

__global__ __launch_bounds__(1024) void scan_partials(
    const int* __restrict__ partials, int* __restrict__ blockoff,
    int* __restrict__ rowptr, int nb, int n) {
  __shared__ int sm[1024];
  int t = threadIdx.x;
  int v = (t < nb) ? partials[t] : 0;
  sm[t] = v;
  __syncthreads();
  for (int off = 1; off < 1024; off <<= 1) {
    int u = (t >= off) ? sm[t - off] : 0;
    __syncthreads();
    sm[t] += u;
    __syncthreads();
  }
  if (t < nb) blockoff[t] = sm[t] - v;   // exclusive
  if (t == 1023) rowptr[n] = sm[1023];   // total = E
}

__global__ __launch_bounds__(256) void scan_blocks(
    const int* __restrict__ deg, const int* __restrict__ blockoff,
    int* __restrict__ rowptr, int n) {
  int base = blockIdx.x * SCHUNK;
  int t = threadIdx.x;
  int lane = t & 63, wave = t >> 6;
  int i0 = base + 2 * t, i1 = i0 + 1;
  int d0 = (i0 < n) ? deg[i0] : 0;
  int d1 = (i1 < n) ? deg[i1] : 0;
  int s = d0 + d1;
  int incl = s;
#pragma unroll
  for (int off = 1; off < 64; off <<= 1) {
    int u = __shfl_up(incl, off);
    if (lane >= off) incl += u;
  }
  __shared__ int wsum[4];
  if (lane == 63) wsum[wave] = incl;
  __syncthreads();
  int woff = 0;
  for (int w = 0; w < wave; ++w) woff += wsum[w];
  int excl = woff + (incl - s) + blockoff[blockIdx.x];
  if (i0 < n) rowptr[i0] = excl;
  if (i1 < n) rowptr[i1] = excl + d0;
}

__global__ void scatter_kernel(const int* __restrict__ src, const int* __restrict__ dst,
                               const float* __restrict__ val,
                               const int* __restrict__ rowptr, int* __restrict__ cursor,
                               int* __restrict__ csr_dst, float* __restrict__ csr_val, int e) {
  int i = blockIdx.x * blockDim.x + threadIdx.x;
  if (i < e) {
    int s = src[i];
    int p = atomicAdd(&cursor[s], 1);
    int idx = rowptr[s] + p;
    csr_dst[idx] = dst[i];
    csr_val[idx] = val[i];
  }
}

// ---------------- per-node attention: lane = (edge-slot, head) -------------
__global__ __launch_bounds__(256) void node_kernel(
    const unsigned short* __restrict__ qb, const unsigned short* __restrict__ kvb,
    const int* __restrict__ rowptr, const int* __restrict__ csr_dst,
    const float* __restrict__ csr_val,
    float* __restrict__ out, int n) {
  int wid = (blockIdx.x * blockDim.x + threadIdx.x) >> 6;
  int lane = threadIdx.x & 63;
  if (wid >= n) return;
  const int head = lane & 7;
  const int eg = lane >> 3;

  // q[head][0..15] -> 16 f32 (scaled already)
  const uint4* qr = (const uint4*)(qb + (size_t)wid * HID + head * 16);
  uint4 q0 = qr[0], q1 = qr[1];
  float qf[16];
  {
    unsigned int qd[8] = {q0.x, q0.y, q0.z, q0.w, q1.x, q1.y, q1.z, q1.w};
#pragma unroll
    for (int j = 0; j < 8; ++j) { qf[2 * j] = blo(qd[j]); qf[2 * j + 1] = bhi(qd[j]); }
  }

  int beg = rowptr[wid], end = rowptr[wid + 1];
  float m = -INFINITY, s = 0.f;
  float o[16];
#pragma unroll
  for (int j = 0; j < 16; ++j) o[j] = 0.f;

  for (int base = beg; base < end; base += 8) {
    int i = base + eg;
    bool valid = i < end;
    int d = valid ? csr_dst[i] : 0;
    float vale = valid ? csr_val[i] : 0.f;

    const uint4* kr = (const uint4*)(kvb + (size_t)d * (2 * HID) + head * 16);
    uint4 ka = kr[0], kb2 = kr[1];     // k dims 0..15
    uint4 va = kr[16], vb2 = kr[17];   // v dims 0..15 (+128 shorts)

    float dot = 0.f;
    {
      unsigned int kd[8] = {ka.x, ka.y, ka.z, ka.w, kb2.x, kb2.y, kb2.z, kb2.w};
#pragma unroll
      for (int j = 0; j < 8; ++j)
        dot += qf[2 * j] * blo(kd[j]) + qf[2 * j + 1] * bhi(kd[j]);
    }
    float score = valid ? dot * vale : -INFINITY;

    // chunk max across the 8 edge slots (same head)
    float mx = score;
    mx = fmaxf(mx, __shfl_xor(mx, 8));
    mx = fmaxf(mx, __shfl_xor(mx, 16));
    mx = fmaxf(mx, __shfl_xor(mx, 32));

    if (!__all(mx <= m + 8.f)) {       // rare: rescale (wave-uniform branch)
      float mn = fmaxf(m, mx);
      float c = __expf(m - mn);        // first chunk: exp(-inf)=0 zeroes s,o
      s *= c;
#pragma unroll
      for (int j = 0; j < 16; ++j) o[j] *= c;
      m = mn;
    }

    float w = __expf(score - m);       // invalid: exp(-inf)=0
    s += w;
    {
      unsigned int vd[8] = {va.x, va.y, va.z, va.w, vb2.x, vb2.y, vb2.z, vb2.w};
#pragma unroll
      for (int j = 0; j < 8; ++j) {
        o[2 * j]     += w * blo(vd[j]);
        o[2 * j + 1] += w * bhi(vd[j]);
      }
    }
  }

  // merge the 8 edge-slot partials (m already common per head)
  s += __shfl_xor(s, 8); s += __shfl_xor(s, 16); s += __shfl_xor(s, 32);
#pragma unroll
  for (int j = 0; j < 16; ++j) {
    o[j] += __shfl_xor(o[j], 8);
    o[j] += __shfl_xor(o[j], 16);
    o[j] += __shfl_xor(o[j], 32);
  }

  float inv = (s > 0.f) ? 1.f / s : 0.f;
  // feature f = d*8 + head; distribute 16 stores: eg handles d = eg, eg+8
#pragma unroll
  for (int dd = 0; dd < 16; ++dd) {
    if (eg == (dd & 7))
      out[(size_t)wid * HID + dd * 8 + head] = o[dd] * inv;
  }
}

// ---------------- launcher ----------------
extern "C" void kernel_launch(void* const* d_in, const int* in_sizes, int n_in,
                              void* d_out, int out_size, void* d_ws, size_t ws_size,
                              hipStream_t stream) {
  const float* h  = (const float*)d_in[0];
  const float* val = (const float*)d_in[1];
  const float* Wq = (const float*)d_in[2];
  const float* bq = (const float*)d_in[3];
  const float* Wk = (const float*)d_in[4];
  const float* bk = (const float*)d_in[5];
  const float* Wv = (const float*)d_in[6];
  const float* bv = (const float*)d_in[7];
  const int* src  = (const int*)d_in[8];
  const int* dst  = (const int*)d_in[9];

  int N = in_sizes[0] / HID;
  int E = in_sizes[8];
  float* out = (float*)d_out;
  int nb = (N + SCHUNK - 1) / SCHUNK;

  // workspace layout (bf16 = unsigned short)
  unsigned short* hb  = (unsigned short*)d_ws;              // N*128
  unsigned short* wb  = hb + (size_t)N * HID;               // 3*128*128
  unsigned short* qb  = wb + 3 * HID * HID;                 // N*128
  unsigned short* kvb = qb + (size_t)N * HID;               // N*256
  int* rowptr  = (int*)(kvb + (size_t)2 * N * HID);         // N+1
  int* deg     = rowptr + (N + 1);                          // N
  int* cursor  = deg + N;                                   // N
  int* partials = cursor + N;                               // nb
  int* blockoff = partials + nb;                            // nb
  int* csr_dst = blockoff + nb;                             // E
  float* csr_val = (float*)(csr_dst + E);                   // E

  hipMemsetAsync(deg, 0, sizeof(int) * 2 * (size_t)N, stream);  // deg + cursor

  int n8_h = N * HID / 8;
  convert_kernel<<<(n8_h + 255) / 256, 256, 0, stream>>>(h, hb, n8_h);
  int n8_w = HID * HID / 8;
  convert3_kernel<<<dim3((n8_w + 255) / 256, 3), 256, 0, stream>>>(Wq, Wk, Wv, wb, n8_w);

  proj_mfma<<<dim3((N + 63) / 64, 3), 256, 0, stream>>>(hb, wb, bq, bk, bv, qb, kvb, N);

  hist_kernel<<<(E + 255) / 256, 256, 0, stream>>>(src, deg, E);
  reduce_blocks<<<nb, 256, 0, stream>>>(deg, partials, N);
  scan_partials<<<1, 1024, 0, stream>>>(partials, blockoff, rowptr, nb, N);
  scan_blocks<<<nb, 256, 0, stream>>>(deg, blockoff, rowptr, N);
  scatter_kernel<<<(E + 255) / 256, 256, 0, stream>>>(
      src, dst, val, rowptr, cursor, csr_dst, csr_val, E);
  node_kernel<<<(N + 3) / 4, 256, 0, stream>>>(
      qb, kvb, rowptr, csr_dst, csr_val, out, N);
}